// Round 1
// baseline (530.576 us; speedup 1.0000x reference)
//
#include <hip/hip_runtime.h>
#include <hip/hip_bf16.h>
#include <cstdint>

// ---------------------------------------------------------------------------
// RoPE Multi-Head Self-Attention, MI355X (gfx950)
// B=32, S=577, E=768, H=12, Dh=64.  Inputs fp32, output fp32 (r6-verified).
// Internally bf16 MFMA / fp32 accumulate; qkv workspace bf16.
// Round 8:
//  [C1,C2] convert x, w_qkv -> bf16 into d_out-as-scratch (dead until K4)
//  [K1] qkv = xb @ wb^T           (pure-bf16, global_load_lds DMA staging)
//  [K2] RoPE in-place on q,k patch rows
//  [K3] flash attention, 512 thr / 128-row Q tile; Ps aliased onto dead Qs
//       LDS region -> 36864 B/block -> 4 blocks/CU (was 2), 32 waves/CU.
//  [K4] out = O @ bf16(w_proj)^T  (A via DMA, B fp32 register-convert, C fp32)
// ---------------------------------------------------------------------------

typedef __attribute__((ext_vector_type(8))) short bf16x8;  // 8 bf16 = 4 VGPRs
typedef __attribute__((ext_vector_type(4))) float f32x4;

#define MFMA16(a, b, c) __builtin_amdgcn_mfma_f32_16x16x32_bf16((a), (b), (c), 0, 0, 0)

#define S_LEN 577
#define NHEAD 12
#define DHEAD 64
#define EMB   768
#define F3    2304   // 3*EMB

// async global->LDS, 16B/lane; LDS dest must be wave-uniform base + lane*16.
__device__ __forceinline__ void gload_lds16(const __hip_bfloat16* g, __hip_bfloat16* l) {
    __builtin_amdgcn_global_load_lds(
        (const __attribute__((address_space(1))) unsigned int*)g,
        (__attribute__((address_space(3))) unsigned int*)l, 16, 0, 0);
}

// load 8 consecutive fp32, convert to bf16 packed in a uint4 (16B)
__device__ __forceinline__ uint4 load8_f32(const float* p) {
    const float4 f0 = *(const float4*)p;
    const float4 f1 = *(const float4*)(p + 4);
    union { uint4 u; __hip_bfloat16 h[8]; } r;
    r.h[0] = __float2bfloat16(f0.x); r.h[1] = __float2bfloat16(f0.y);
    r.h[2] = __float2bfloat16(f0.z); r.h[3] = __float2bfloat16(f0.w);
    r.h[4] = __float2bfloat16(f1.x); r.h[5] = __float2bfloat16(f1.y);
    r.h[6] = __float2bfloat16(f1.z); r.h[7] = __float2bfloat16(f1.w);
    return r.u;
}

// ---------------------------------------------------------------------------
// C1/C2: fp32 -> bf16 bulk convert (n must be a multiple of 8; ours are)
// ---------------------------------------------------------------------------
__global__ __launch_bounds__(256) void cvt_f32_bf16(
    const float* __restrict__ src, __hip_bfloat16* __restrict__ dst, int n8)
{
    const int i = blockIdx.x * 256 + threadIdx.x;
    if (i < n8)
        *(uint4*)(dst + (size_t)i * 8) = load8_f32(src + (size_t)i * 8);
}

// ---------------------------------------------------------------------------
// K1/K4: C[m][n] = sum_k A[m][k] * B[n][k]
// A: bf16, row stride lda, staged via global_load_lds DMA.
// B: BF32 ? fp32 register-convert staging : bf16 DMA staging. Row stride ldb.
// C: CF32 ? fp32 : bf16.  N%128==0, K%32==0; M guarded.
// 128x128 tile, BK=32, 16x16x32 MFMA, 4 waves x 4x4 acc frags (m97 structure).
// ---------------------------------------------------------------------------
template<bool BF32, bool CF32>
__global__ __launch_bounds__(256) void gemm_a_dma(
    const __hip_bfloat16* __restrict__ A, int lda,
    const void* __restrict__ Bv, int ldb,
    void* __restrict__ Cv, int M, int N, int K)
{
    __shared__ __hip_bfloat16 As[128 * 32];   // [row][k], 64B rows (DMA layout)
    __shared__ __hip_bfloat16 Bs[128 * 32];

    const int t      = threadIdx.x;
    const int l      = t & 63;
    const int w      = t >> 6;
    const int lane15 = l & 15;
    const int quad   = l >> 4;

    const int n0 = blockIdx.x * 128;
    const int m0 = blockIdx.y * 128;
    const int wm = (w >> 1) * 64;
    const int wn = (w & 1) * 64;

    const int srow   = t >> 2;   // 0..63
    const int schunk = t & 3;    // 0..3 (16B chunks)

    int ar0 = m0 + srow;       if (ar0 > M - 1) ar0 = M - 1;
    int ar1 = m0 + 64 + srow;  if (ar1 > M - 1) ar1 = M - 1;
    const int br0 = n0 + srow;
    const int br1 = n0 + 64 + srow;

    const __hip_bfloat16* pa0 = A + (size_t)ar0 * lda + schunk * 8;
    const __hip_bfloat16* pa1 = A + (size_t)ar1 * lda + schunk * 8;
    const size_t b0off = (size_t)br0 * ldb + schunk * 8;
    const size_t b1off = (size_t)br1 * ldb + schunk * 8;

    __hip_bfloat16* lAs0 = As + srow * 32 + schunk * 8;          // == As + t*8
    __hip_bfloat16* lAs1 = As + (64 + srow) * 32 + schunk * 8;
    __hip_bfloat16* lBs0 = Bs + srow * 32 + schunk * 8;
    __hip_bfloat16* lBs1 = Bs + (64 + srow) * 32 + schunk * 8;

    f32x4 acc[4][4] = {};

    for (int k0 = 0; k0 < K; k0 += 32) {
        uint4 vb0, vb1;
        if constexpr (BF32) {   // issue B global loads before barrier (overlap)
            vb0 = load8_f32((const float*)Bv + b0off + k0);
            vb1 = load8_f32((const float*)Bv + b1off + k0);
        }
        __syncthreads();        // prior iter's frag reads complete
        gload_lds16(pa0 + k0, lAs0);
        gload_lds16(pa1 + k0, lAs1);
        if constexpr (BF32) {
            *(uint4*)lBs0 = vb0;
            *(uint4*)lBs1 = vb1;
        } else {
            gload_lds16((const __hip_bfloat16*)Bv + b0off + k0, lBs0);
            gload_lds16((const __hip_bfloat16*)Bv + b1off + k0, lBs1);
        }
        __syncthreads();        // compiler drains vmcnt+lgkmcnt before barrier

        bf16x8 a[4], b[4];
        #pragma unroll
        for (int i = 0; i < 4; ++i)
            a[i] = *(const bf16x8*)(As + (wm + i * 16 + lane15) * 32 + quad * 8);
        #pragma unroll
        for (int j = 0; j < 4; ++j)
            b[j] = *(const bf16x8*)(Bs + (wn + j * 16 + lane15) * 32 + quad * 8);

        #pragma unroll
        for (int i = 0; i < 4; ++i)
            #pragma unroll
            for (int j = 0; j < 4; ++j)
                acc[i][j] = MFMA16(a[i], b[j], acc[i][j]);
    }

    // epilogue: C/D layout col=lane&15, row=quad*4+reg
    #pragma unroll
    for (int i = 0; i < 4; ++i) {
        #pragma unroll
        for (int r = 0; r < 4; ++r) {
            const int m = m0 + wm + i * 16 + quad * 4 + r;
            if (m < M) {
                #pragma unroll
                for (int j = 0; j < 4; ++j) {
                    const int n = n0 + wn + j * 16 + lane15;
                    if constexpr (CF32)
                        ((float*)Cv)[(size_t)m * N + n] = acc[i][j][r];
                    else
                        ((__hip_bfloat16*)Cv)[(size_t)m * N + n] = __float2bfloat16(acc[i][j][r]);
                }
            }
        }
    }
}

// ---------------------------------------------------------------------------
// K2: RoPE in-place on q and k for patch tokens (s >= 1) — r6-verified.
// ---------------------------------------------------------------------------
__global__ __launch_bounds__(256) void rope_kernel(__hip_bfloat16* __restrict__ qkv)
{
    const int p = blockIdx.x;    // 0..575 patch index
    const int b = blockIdx.y;
    const int l = threadIdx.x & 63;
    const int w = threadIdx.x >> 6;

    const int jj   = l & 31;
    const float i2 = (float)((jj >> 1) * 2);
    const float dv = __expf(-i2 * 0.28782313662425576f);   // ln(10000)/32
    const float inv = 1.0f / (23.0f + 1e-8f);
    const float cx = (float)(p % 24) * inv;
    const float cy = (float)(p / 24) * inv;
    const float ang = ((l < 32) ? cx : cy) * dv;
    const float c = __cosf(ang);
    const float s = __sinf(ang);
    const int nb = (l & 32) | ((jj + 31) & 31);   // lane of (j-1)%32, same half

    const size_t rowbase = ((size_t)(b * S_LEN + 1 + p)) * F3;

    for (int pr = w; pr < 24; pr += 4) {
        const int part = pr / 12;    // 0=q, 1=k
        const int h    = pr % 12;
        const size_t off = rowbase + (size_t)part * EMB + h * DHEAD + l;
        float v  = __bfloat162float(qkv[off]);
        float vp = __shfl(v, nb, 64);
        qkv[off] = __float2bfloat16(v * c + vp * s);
    }
}

// ---------------------------------------------------------------------------
// K3: MFMA flash attention, 512 threads (8 waves), Q tile = 128 rows.
// grid (qt=5, h=12, b=32). Wave w owns q rows w*16..w*16+15 of the tile.
// K/V tiles of 64 keys; staging split across 512 threads (2x amortized).
// Q pre-scaled by 0.125. O written with row stride ldo (aliased onto qkv's
// q-region; each block overwrites exactly the q-cells only it reads).
//
// Round 8: Ps is aliased onto the Qs LDS region. Qs is consumed into
// registers (qf0/qf1) ONCE before the K/V loop, so its LDS is dead for the
// rest of the kernel; Ps[w][x][y] == Qs[w*16+x][y] preserves the exact same
// per-wave row partition and bank behavior. LDS: 55296 -> 36864 B/block,
// so 4 blocks/CU (2048 thr = HW max) instead of 2 -> 32 waves/CU.
// Safety: the first in-loop __syncthreads() (s0=0) orders all waves' Qs
// frag reads before any wave's first P write; P write->read is wave-private
// with an explicit lgkmcnt(0) drain (same-wave safety proven r4/r5).
// ---------------------------------------------------------------------------
__global__ __launch_bounds__(512, 8) void attn_kernel(
    const __hip_bfloat16* __restrict__ qkv,
    __hip_bfloat16* __restrict__ attn_out, int ldo)
{
    __shared__ __hip_bfloat16 Qs[128][72];     // Q frags, then aliased as Ps
    __shared__ __hip_bfloat16 Ks[64][72];
    __shared__ __hip_bfloat16 Vt[64][72];      // transposed: Vt[d][s]

    const int t      = threadIdx.x;
    const int l      = t & 63;
    const int w      = t >> 6;     // 0..7
    const int lane15 = l & 15;
    const int quad   = l >> 4;

    const int q0 = blockIdx.x * 128;
    const int h  = blockIdx.y;
    const int b  = blockIdx.z;

    // ---- stage Q (scaled): row = t>>2 (0..127), seg = t&3 (16 elems) ----
    {
        const int row = t >> 2, seg = t & 3;
        int gq = q0 + row; if (gq > S_LEN - 1) gq = S_LEN - 1;
        const uint4* src = (const uint4*)(qkv + (size_t)(b * S_LEN + gq) * F3 + h * DHEAD + seg * 16);
        uint4 u0 = src[0], u1 = src[1];
        const __hip_bfloat16* e0 = (const __hip_bfloat16*)&u0;
        const __hip_bfloat16* e1 = (const __hip_bfloat16*)&u1;
        #pragma unroll
        for (int i = 0; i < 8; ++i) {
            Qs[row][seg * 16 + i]     = __float2bfloat16(__bfloat162float(e0[i]) * 0.125f);
            Qs[row][seg * 16 + 8 + i] = __float2bfloat16(__bfloat162float(e1[i]) * 0.125f);
        }
    }
    __syncthreads();

    // A-operand frags for Q: A[m=lane&15][k=quad*8+j]  (held whole loop)
    bf16x8 qf0 = *(const bf16x8*)&Qs[w * 16 + lane15][quad * 8];
    bf16x8 qf1 = *(const bf16x8*)&Qs[w * 16 + lane15][32 + quad * 8];

    f32x4 o[4] = {};                       // O[q=quad*4+r][d=ci*16+lane15]
    float m_i[4] = {-3.0e38f, -3.0e38f, -3.0e38f, -3.0e38f};
    float l_i[4] = {0.f, 0.f, 0.f, 0.f};

    for (int s0 = 0; s0 < S_LEN; s0 += 64) {
        __syncthreads();   // prior tile's Ks/Vt (and all waves' Qs-frag) reads complete
        // ---- stage K tile: row = t>>3 (0..63), seg8 = t&7 (8 elems) ----
        {
            const int row = t >> 3, seg8 = t & 7;
            int gk = s0 + row; if (gk > S_LEN - 1) gk = S_LEN - 1;
            const uint4* src = (const uint4*)(qkv + (size_t)(b * S_LEN + gk) * F3 + EMB + h * DHEAD);
            *(uint4*)&Ks[row][seg8 * 8] = src[seg8];
        }
        // ---- stage V tile transposed: s = t&63, dg = t>>6 (8 dims) ----
        {
            const int s = t & 63, dg = t >> 6;
            int gk = s0 + s; if (gk > S_LEN - 1) gk = S_LEN - 1;
            const uint4* src = (const uint4*)(qkv + (size_t)(b * S_LEN + gk) * F3 + 2 * EMB + h * DHEAD);
            uint4 u0 = src[dg];
            const __hip_bfloat16* e0 = (const __hip_bfloat16*)&u0;
            #pragma unroll
            for (int i = 0; i < 8; ++i)
                Vt[dg * 8 + i][s] = e0[i];
        }
        __syncthreads();

        // ---- S = Q K^T (16 q rows x 64 keys per wave) ----
        f32x4 sf[4];
        #pragma unroll
        for (int nt = 0; nt < 4; ++nt) {
            f32x4 z = {0.f, 0.f, 0.f, 0.f};
            bf16x8 k0f = *(const bf16x8*)&Ks[nt * 16 + lane15][quad * 8];
            bf16x8 k1f = *(const bf16x8*)&Ks[nt * 16 + lane15][32 + quad * 8];
            z = MFMA16(qf0, k0f, z);
            z = MFMA16(qf1, k1f, z);
            sf[nt] = z;
        }
        #pragma unroll
        for (int nt = 0; nt < 4; ++nt) {
            if (s0 + nt * 16 + lane15 >= S_LEN)
                sf[nt] = (f32x4){-1e30f, -1e30f, -1e30f, -1e30f};
        }

        // ---- online softmax; rows r=0..3 are q rows quad*4+r ----
        float alpha[4];
        #pragma unroll
        for (int r = 0; r < 4; ++r) {
            float mx = fmaxf(fmaxf(sf[0][r], sf[1][r]), fmaxf(sf[2][r], sf[3][r]));
            #pragma unroll
            for (int off = 1; off < 16; off <<= 1)
                mx = fmaxf(mx, __shfl_xor(mx, off, 64));
            float mnew = fmaxf(m_i[r], mx);
            alpha[r] = __expf(m_i[r] - mnew);
            m_i[r] = mnew;
        }

        float pv[4][4];   // [nt][r]
        #pragma unroll
        for (int nt = 0; nt < 4; ++nt)
            #pragma unroll
            for (int r = 0; r < 4; ++r)
                pv[nt][r] = __expf(sf[nt][r] - m_i[r]);

        #pragma unroll
        for (int r = 0; r < 4; ++r) {
            float sum = pv[0][r] + pv[1][r] + pv[2][r] + pv[3][r];
            #pragma unroll
            for (int off = 1; off < 16; off <<= 1)
                sum += __shfl_xor(sum, off, 64);
            l_i[r] = l_i[r] * alpha[r] + sum;
        }

        #pragma unroll
        for (int ci = 0; ci < 4; ++ci)
            #pragma unroll
            for (int r = 0; r < 4; ++r)
                o[ci][r] *= alpha[r];

        // ---- P: C-layout -> LDS (aliased onto dead Qs rows of THIS wave)
        //      -> A-layout (wave-local; drain own LDS writes only) ----
        #pragma unroll
        for (int nt = 0; nt < 4; ++nt)
            #pragma unroll
            for (int r = 0; r < 4; ++r)
                Qs[w * 16 + quad * 4 + r][nt * 16 + lane15] = __float2bfloat16(pv[nt][r]);
        asm volatile("s_waitcnt lgkmcnt(0)" ::: "memory");

        // ---- O += P V ----
        #pragma unroll
        for (int s32 = 0; s32 < 2; ++s32) {
            bf16x8 pa = *(const bf16x8*)&Qs[w * 16 + lane15][s32 * 32 + quad * 8];
            #pragma unroll
            for (int ci = 0; ci < 4; ++ci) {
                bf16x8 vb = *(const bf16x8*)&Vt[ci * 16 + lane15][s32 * 32 + quad * 8];
                o[ci] = MFMA16(pa, vb, o[ci]);
            }
        }
    }

    // ---- epilogue: O / l_i -> attn_out[(b,q) row, h*64+d] (bf16 ws) ----
    #pragma unroll
    for (int r = 0; r < 4; ++r) {
        const int q = q0 + w * 16 + quad * 4 + r;
        if (q < S_LEN) {
            const float rl = 1.0f / l_i[r];
            #pragma unroll
            for (int ci = 0; ci < 4; ++ci) {
                attn_out[(size_t)(b * S_LEN + q) * ldo + h * DHEAD + ci * 16 + lane15] =
                    __float2bfloat16(o[ci][r] * rl);
            }
        }
    }
}

// ---------------------------------------------------------------------------
extern "C" void kernel_launch(void* const* d_in, const int* in_sizes, int n_in,
                              void* d_out, int out_size, void* d_ws, size_t ws_size,
                              hipStream_t stream) {
    const float* x      = (const float*)d_in[0];
    const float* w_qkv  = (const float*)d_in[1];
    const float* w_proj = (const float*)d_in[2];
    for (int i = 0; i < n_in; ++i) {
        if      (in_sizes[i] == 32 * S_LEN * EMB) x      = (const float*)d_in[i];
        else if (in_sizes[i] == F3 * EMB)         w_qkv  = (const float*)d_in[i];
        else if (in_sizes[i] == EMB * EMB)        w_proj = (const float*)d_in[i];
    }
    float* out = (float*)d_out;     // fp32 output (r6-verified)

    const int Mrows = 32 * S_LEN;           // 18464
    const int NX    = Mrows * EMB;          // 14,180,352 (mult of 8)
    const int NWQ   = F3 * EMB;             // 1,769,472  (mult of 8)

    __hip_bfloat16* qkv = (__hip_bfloat16*)d_ws;        // [M][2304] bf16, 81.1 MiB
    // d_out as scratch until K4 overwrites it: xb (28.4 MB) + wb (3.4 MB) < 56.7 MB
    __hip_bfloat16* xb  = (__hip_bfloat16*)d_out;
    __hip_bfloat16* wb  = xb + (size_t)NX;

    // C1/C2: fp32 -> bf16 converts into d_out scratch
    cvt_f32_bf16<<<NX / 8 / 256, 256, 0, stream>>>(x, xb, NX / 8);
    cvt_f32_bf16<<<NWQ / 8 / 256, 256, 0, stream>>>(w_qkv, wb, NWQ / 8);
    // K1: qkv = xb @ wb^T  (pure-bf16 DMA staging, bf16 C)
    gemm_a_dma<false, false><<<dim3(F3 / 128, (Mrows + 127) / 128), 256, 0, stream>>>(
        xb, EMB, wb, EMB, qkv, Mrows, F3, EMB);
    // K2: RoPE on q,k patch rows
    rope_kernel<<<dim3(576, 32), 256, 0, stream>>>(qkv);
    // K3: attention (512 thr, 128-row Q tiles); O overwrites q-region of qkv
    attn_kernel<<<dim3((S_LEN + 127) / 128, NHEAD, 32), 512, 0, stream>>>(qkv, qkv, F3);
    // K4: out = O @ bf16(w_proj)^T  (A DMA bf16 stride F3; B fp32 convert; C fp32)
    gemm_a_dma<true, true><<<dim3(EMB / 128, (Mrows + 127) / 128), 256, 0, stream>>>(
        qkv, F3, w_proj, EMB, out, Mrows, EMB, EMB);
}

// Round 2
// 416.713 us; speedup vs baseline: 1.2732x; 1.2732x over previous
//
#include <hip/hip_runtime.h>
#include <hip/hip_bf16.h>
#include <cstdint>

// ---------------------------------------------------------------------------
// RoPE Multi-Head Self-Attention, MI355X (gfx950)
// B=32, S=577, E=768, H=12, Dh=64.  Inputs fp32, output fp32 (r6-verified).
// Internally bf16 MFMA / fp32 accumulate; qkv workspace bf16.
// Round 9:
//  [C1,C2] convert x, w_qkv -> bf16 into d_out-as-scratch (dead until K4)
//  [K1] qkv = xb @ wb^T           (pure-bf16, global_load_lds DMA staging)
//  [K2] RoPE in-place on q,k patch rows
//  [K3] flash attention, 512 thr / 128-row Q tile; Ps aliased onto dead Qs
//       LDS region -> 36864 B/block -> 4 blocks/CU, 32 waves/CU.
//       r8 POST-MORTEM: __launch_bounds__(512,8) capped VGPR at 64 -> compiler
//       spilled (VGPR 52->32, FETCH +422MB, WRITE +371MB, 243us). Reverted to
//       plain __launch_bounds__(512): natural 52 VGPR <= 64 already permits
//       4 blocks/CU -- the cap was unnecessary AND harmful.
//  [K4] out = O @ bf16(w_proj)^T  (A via DMA, B fp32 register-convert, C fp32)
// ---------------------------------------------------------------------------

typedef __attribute__((ext_vector_type(8))) short bf16x8;  // 8 bf16 = 4 VGPRs
typedef __attribute__((ext_vector_type(4))) float f32x4;

#define MFMA16(a, b, c) __builtin_amdgcn_mfma_f32_16x16x32_bf16((a), (b), (c), 0, 0, 0)

#define S_LEN 577
#define NHEAD 12
#define DHEAD 64
#define EMB   768
#define F3    2304   // 3*EMB

// async global->LDS, 16B/lane; LDS dest must be wave-uniform base + lane*16.
__device__ __forceinline__ void gload_lds16(const __hip_bfloat16* g, __hip_bfloat16* l) {
    __builtin_amdgcn_global_load_lds(
        (const __attribute__((address_space(1))) unsigned int*)g,
        (__attribute__((address_space(3))) unsigned int*)l, 16, 0, 0);
}

// load 8 consecutive fp32, convert to bf16 packed in a uint4 (16B)
__device__ __forceinline__ uint4 load8_f32(const float* p) {
    const float4 f0 = *(const float4*)p;
    const float4 f1 = *(const float4*)(p + 4);
    union { uint4 u; __hip_bfloat16 h[8]; } r;
    r.h[0] = __float2bfloat16(f0.x); r.h[1] = __float2bfloat16(f0.y);
    r.h[2] = __float2bfloat16(f0.z); r.h[3] = __float2bfloat16(f0.w);
    r.h[4] = __float2bfloat16(f1.x); r.h[5] = __float2bfloat16(f1.y);
    r.h[6] = __float2bfloat16(f1.z); r.h[7] = __float2bfloat16(f1.w);
    return r.u;
}

// ---------------------------------------------------------------------------
// C1/C2: fp32 -> bf16 bulk convert (n must be a multiple of 8; ours are)
// ---------------------------------------------------------------------------
__global__ __launch_bounds__(256) void cvt_f32_bf16(
    const float* __restrict__ src, __hip_bfloat16* __restrict__ dst, int n8)
{
    const int i = blockIdx.x * 256 + threadIdx.x;
    if (i < n8)
        *(uint4*)(dst + (size_t)i * 8) = load8_f32(src + (size_t)i * 8);
}

// ---------------------------------------------------------------------------
// K1/K4: C[m][n] = sum_k A[m][k] * B[n][k]
// A: bf16, row stride lda, staged via global_load_lds DMA.
// B: BF32 ? fp32 register-convert staging : bf16 DMA staging. Row stride ldb.
// C: CF32 ? fp32 : bf16.  N%128==0, K%32==0; M guarded.
// 128x128 tile, BK=32, 16x16x32 MFMA, 4 waves x 4x4 acc frags (m97 structure).
// ---------------------------------------------------------------------------
template<bool BF32, bool CF32>
__global__ __launch_bounds__(256) void gemm_a_dma(
    const __hip_bfloat16* __restrict__ A, int lda,
    const void* __restrict__ Bv, int ldb,
    void* __restrict__ Cv, int M, int N, int K)
{
    __shared__ __hip_bfloat16 As[128 * 32];   // [row][k], 64B rows (DMA layout)
    __shared__ __hip_bfloat16 Bs[128 * 32];

    const int t      = threadIdx.x;
    const int l      = t & 63;
    const int w      = t >> 6;
    const int lane15 = l & 15;
    const int quad   = l >> 4;

    const int n0 = blockIdx.x * 128;
    const int m0 = blockIdx.y * 128;
    const int wm = (w >> 1) * 64;
    const int wn = (w & 1) * 64;

    const int srow   = t >> 2;   // 0..63
    const int schunk = t & 3;    // 0..3 (16B chunks)

    int ar0 = m0 + srow;       if (ar0 > M - 1) ar0 = M - 1;
    int ar1 = m0 + 64 + srow;  if (ar1 > M - 1) ar1 = M - 1;
    const int br0 = n0 + srow;
    const int br1 = n0 + 64 + srow;

    const __hip_bfloat16* pa0 = A + (size_t)ar0 * lda + schunk * 8;
    const __hip_bfloat16* pa1 = A + (size_t)ar1 * lda + schunk * 8;
    const size_t b0off = (size_t)br0 * ldb + schunk * 8;
    const size_t b1off = (size_t)br1 * ldb + schunk * 8;

    __hip_bfloat16* lAs0 = As + srow * 32 + schunk * 8;          // == As + t*8
    __hip_bfloat16* lAs1 = As + (64 + srow) * 32 + schunk * 8;
    __hip_bfloat16* lBs0 = Bs + srow * 32 + schunk * 8;
    __hip_bfloat16* lBs1 = Bs + (64 + srow) * 32 + schunk * 8;

    f32x4 acc[4][4] = {};

    for (int k0 = 0; k0 < K; k0 += 32) {
        uint4 vb0, vb1;
        if constexpr (BF32) {   // issue B global loads before barrier (overlap)
            vb0 = load8_f32((const float*)Bv + b0off + k0);
            vb1 = load8_f32((const float*)Bv + b1off + k0);
        }
        __syncthreads();        // prior iter's frag reads complete
        gload_lds16(pa0 + k0, lAs0);
        gload_lds16(pa1 + k0, lAs1);
        if constexpr (BF32) {
            *(uint4*)lBs0 = vb0;
            *(uint4*)lBs1 = vb1;
        } else {
            gload_lds16((const __hip_bfloat16*)Bv + b0off + k0, lBs0);
            gload_lds16((const __hip_bfloat16*)Bv + b1off + k0, lBs1);
        }
        __syncthreads();        // compiler drains vmcnt+lgkmcnt before barrier

        bf16x8 a[4], b[4];
        #pragma unroll
        for (int i = 0; i < 4; ++i)
            a[i] = *(const bf16x8*)(As + (wm + i * 16 + lane15) * 32 + quad * 8);
        #pragma unroll
        for (int j = 0; j < 4; ++j)
            b[j] = *(const bf16x8*)(Bs + (wn + j * 16 + lane15) * 32 + quad * 8);

        #pragma unroll
        for (int i = 0; i < 4; ++i)
            #pragma unroll
            for (int j = 0; j < 4; ++j)
                acc[i][j] = MFMA16(a[i], b[j], acc[i][j]);
    }

    // epilogue: C/D layout col=lane&15, row=quad*4+reg
    #pragma unroll
    for (int i = 0; i < 4; ++i) {
        #pragma unroll
        for (int r = 0; r < 4; ++r) {
            const int m = m0 + wm + i * 16 + quad * 4 + r;
            if (m < M) {
                #pragma unroll
                for (int j = 0; j < 4; ++j) {
                    const int n = n0 + wn + j * 16 + lane15;
                    if constexpr (CF32)
                        ((float*)Cv)[(size_t)m * N + n] = acc[i][j][r];
                    else
                        ((__hip_bfloat16*)Cv)[(size_t)m * N + n] = __float2bfloat16(acc[i][j][r]);
                }
            }
        }
    }
}

// ---------------------------------------------------------------------------
// K2: RoPE in-place on q and k for patch tokens (s >= 1) — r6-verified.
// ---------------------------------------------------------------------------
__global__ __launch_bounds__(256) void rope_kernel(__hip_bfloat16* __restrict__ qkv)
{
    const int p = blockIdx.x;    // 0..575 patch index
    const int b = blockIdx.y;
    const int l = threadIdx.x & 63;
    const int w = threadIdx.x >> 6;

    const int jj   = l & 31;
    const float i2 = (float)((jj >> 1) * 2);
    const float dv = __expf(-i2 * 0.28782313662425576f);   // ln(10000)/32
    const float inv = 1.0f / (23.0f + 1e-8f);
    const float cx = (float)(p % 24) * inv;
    const float cy = (float)(p / 24) * inv;
    const float ang = ((l < 32) ? cx : cy) * dv;
    const float c = __cosf(ang);
    const float s = __sinf(ang);
    const int nb = (l & 32) | ((jj + 31) & 31);   // lane of (j-1)%32, same half

    const size_t rowbase = ((size_t)(b * S_LEN + 1 + p)) * F3;

    for (int pr = w; pr < 24; pr += 4) {
        const int part = pr / 12;    // 0=q, 1=k
        const int h    = pr % 12;
        const size_t off = rowbase + (size_t)part * EMB + h * DHEAD + l;
        float v  = __bfloat162float(qkv[off]);
        float vp = __shfl(v, nb, 64);
        qkv[off] = __float2bfloat16(v * c + vp * s);
    }
}

// ---------------------------------------------------------------------------
// K3: MFMA flash attention, 512 threads (8 waves), Q tile = 128 rows.
// grid (qt=5, h=12, b=32). Wave w owns q rows w*16..w*16+15 of the tile.
// K/V tiles of 64 keys; staging split across 512 threads (2x amortized).
// Q pre-scaled by 0.125. O written with row stride ldo (aliased onto qkv's
// q-region; each block overwrites exactly the q-cells only it reads).
//
// Ps aliased onto the Qs LDS region (Qs dead after frag load): LDS
// 55296 -> 36864 B/block -> 4 blocks/CU (2048 thr = HW max).
// Safety: first in-loop __syncthreads() (s0=0) orders all waves' Qs frag
// reads before any wave's first P write; P write->read is wave-private with
// an explicit lgkmcnt(0) drain (same-wave safety proven r4/r5).
// NO min-waves launch_bounds arg: r8 showed cap=64 forces spills.
// ---------------------------------------------------------------------------
__global__ __launch_bounds__(512) void attn_kernel(
    const __hip_bfloat16* __restrict__ qkv,
    __hip_bfloat16* __restrict__ attn_out, int ldo)
{
    __shared__ __hip_bfloat16 Qs[128][72];     // Q frags, then aliased as Ps
    __shared__ __hip_bfloat16 Ks[64][72];
    __shared__ __hip_bfloat16 Vt[64][72];      // transposed: Vt[d][s]

    const int t      = threadIdx.x;
    const int l      = t & 63;
    const int w      = t >> 6;     // 0..7
    const int lane15 = l & 15;
    const int quad   = l >> 4;

    const int q0 = blockIdx.x * 128;
    const int h  = blockIdx.y;
    const int b  = blockIdx.z;

    // ---- stage Q (scaled): row = t>>2 (0..127), seg = t&3 (16 elems) ----
    {
        const int row = t >> 2, seg = t & 3;
        int gq = q0 + row; if (gq > S_LEN - 1) gq = S_LEN - 1;
        const uint4* src = (const uint4*)(qkv + (size_t)(b * S_LEN + gq) * F3 + h * DHEAD + seg * 16);
        uint4 u0 = src[0], u1 = src[1];
        const __hip_bfloat16* e0 = (const __hip_bfloat16*)&u0;
        const __hip_bfloat16* e1 = (const __hip_bfloat16*)&u1;
        #pragma unroll
        for (int i = 0; i < 8; ++i) {
            Qs[row][seg * 16 + i]     = __float2bfloat16(__bfloat162float(e0[i]) * 0.125f);
            Qs[row][seg * 16 + 8 + i] = __float2bfloat16(__bfloat162float(e1[i]) * 0.125f);
        }
    }
    __syncthreads();

    // A-operand frags for Q: A[m=lane&15][k=quad*8+j]  (held whole loop)
    bf16x8 qf0 = *(const bf16x8*)&Qs[w * 16 + lane15][quad * 8];
    bf16x8 qf1 = *(const bf16x8*)&Qs[w * 16 + lane15][32 + quad * 8];

    f32x4 o[4] = {};                       // O[q=quad*4+r][d=ci*16+lane15]
    float m_i[4] = {-3.0e38f, -3.0e38f, -3.0e38f, -3.0e38f};
    float l_i[4] = {0.f, 0.f, 0.f, 0.f};

    for (int s0 = 0; s0 < S_LEN; s0 += 64) {
        __syncthreads();   // prior tile's Ks/Vt (and all waves' Qs-frag) reads complete
        // ---- stage K tile: row = t>>3 (0..63), seg8 = t&7 (8 elems) ----
        {
            const int row = t >> 3, seg8 = t & 7;
            int gk = s0 + row; if (gk > S_LEN - 1) gk = S_LEN - 1;
            const uint4* src = (const uint4*)(qkv + (size_t)(b * S_LEN + gk) * F3 + EMB + h * DHEAD);
            *(uint4*)&Ks[row][seg8 * 8] = src[seg8];
        }
        // ---- stage V tile transposed: s = t&63, dg = t>>6 (8 dims) ----
        {
            const int s = t & 63, dg = t >> 6;
            int gk = s0 + s; if (gk > S_LEN - 1) gk = S_LEN - 1;
            const uint4* src = (const uint4*)(qkv + (size_t)(b * S_LEN + gk) * F3 + 2 * EMB + h * DHEAD);
            uint4 u0 = src[dg];
            const __hip_bfloat16* e0 = (const __hip_bfloat16*)&u0;
            #pragma unroll
            for (int i = 0; i < 8; ++i)
                Vt[dg * 8 + i][s] = e0[i];
        }
        __syncthreads();

        // ---- S = Q K^T (16 q rows x 64 keys per wave) ----
        f32x4 sf[4];
        #pragma unroll
        for (int nt = 0; nt < 4; ++nt) {
            f32x4 z = {0.f, 0.f, 0.f, 0.f};
            bf16x8 k0f = *(const bf16x8*)&Ks[nt * 16 + lane15][quad * 8];
            bf16x8 k1f = *(const bf16x8*)&Ks[nt * 16 + lane15][32 + quad * 8];
            z = MFMA16(qf0, k0f, z);
            z = MFMA16(qf1, k1f, z);
            sf[nt] = z;
        }
        #pragma unroll
        for (int nt = 0; nt < 4; ++nt) {
            if (s0 + nt * 16 + lane15 >= S_LEN)
                sf[nt] = (f32x4){-1e30f, -1e30f, -1e30f, -1e30f};
        }

        // ---- online softmax; rows r=0..3 are q rows quad*4+r ----
        float alpha[4];
        #pragma unroll
        for (int r = 0; r < 4; ++r) {
            float mx = fmaxf(fmaxf(sf[0][r], sf[1][r]), fmaxf(sf[2][r], sf[3][r]));
            #pragma unroll
            for (int off = 1; off < 16; off <<= 1)
                mx = fmaxf(mx, __shfl_xor(mx, off, 64));
            float mnew = fmaxf(m_i[r], mx);
            alpha[r] = __expf(m_i[r] - mnew);
            m_i[r] = mnew;
        }

        float pv[4][4];   // [nt][r]
        #pragma unroll
        for (int nt = 0; nt < 4; ++nt)
            #pragma unroll
            for (int r = 0; r < 4; ++r)
                pv[nt][r] = __expf(sf[nt][r] - m_i[r]);

        #pragma unroll
        for (int r = 0; r < 4; ++r) {
            float sum = pv[0][r] + pv[1][r] + pv[2][r] + pv[3][r];
            #pragma unroll
            for (int off = 1; off < 16; off <<= 1)
                sum += __shfl_xor(sum, off, 64);
            l_i[r] = l_i[r] * alpha[r] + sum;
        }

        #pragma unroll
        for (int ci = 0; ci < 4; ++ci)
            #pragma unroll
            for (int r = 0; r < 4; ++r)
                o[ci][r] *= alpha[r];

        // ---- P: C-layout -> LDS (aliased onto dead Qs rows of THIS wave)
        //      -> A-layout (wave-local; drain own LDS writes only) ----
        #pragma unroll
        for (int nt = 0; nt < 4; ++nt)
            #pragma unroll
            for (int r = 0; r < 4; ++r)
                Qs[w * 16 + quad * 4 + r][nt * 16 + lane15] = __float2bfloat16(pv[nt][r]);
        asm volatile("s_waitcnt lgkmcnt(0)" ::: "memory");

        // ---- O += P V ----
        #pragma unroll
        for (int s32 = 0; s32 < 2; ++s32) {
            bf16x8 pa = *(const bf16x8*)&Qs[w * 16 + lane15][s32 * 32 + quad * 8];
            #pragma unroll
            for (int ci = 0; ci < 4; ++ci) {
                bf16x8 vb = *(const bf16x8*)&Vt[ci * 16 + lane15][s32 * 32 + quad * 8];
                o[ci] = MFMA16(pa, vb, o[ci]);
            }
        }
    }

    // ---- epilogue: O / l_i -> attn_out[(b,q) row, h*64+d] (bf16 ws) ----
    #pragma unroll
    for (int r = 0; r < 4; ++r) {
        const int q = q0 + w * 16 + quad * 4 + r;
        if (q < S_LEN) {
            const float rl = 1.0f / l_i[r];
            #pragma unroll
            for (int ci = 0; ci < 4; ++ci) {
                attn_out[(size_t)(b * S_LEN + q) * ldo + h * DHEAD + ci * 16 + lane15] =
                    __float2bfloat16(o[ci][r] * rl);
            }
        }
    }
}

// ---------------------------------------------------------------------------
extern "C" void kernel_launch(void* const* d_in, const int* in_sizes, int n_in,
                              void* d_out, int out_size, void* d_ws, size_t ws_size,
                              hipStream_t stream) {
    const float* x      = (const float*)d_in[0];
    const float* w_qkv  = (const float*)d_in[1];
    const float* w_proj = (const float*)d_in[2];
    for (int i = 0; i < n_in; ++i) {
        if      (in_sizes[i] == 32 * S_LEN * EMB) x      = (const float*)d_in[i];
        else if (in_sizes[i] == F3 * EMB)         w_qkv  = (const float*)d_in[i];
        else if (in_sizes[i] == EMB * EMB)        w_proj = (const float*)d_in[i];
    }
    float* out = (float*)d_out;     // fp32 output (r6-verified)

    const int Mrows = 32 * S_LEN;           // 18464
    const int NX    = Mrows * EMB;          // 14,180,352 (mult of 8)
    const int NWQ   = F3 * EMB;             // 1,769,472  (mult of 8)

    __hip_bfloat16* qkv = (__hip_bfloat16*)d_ws;        // [M][2304] bf16, 81.1 MiB
    // d_out as scratch until K4 overwrites it: xb (28.4 MB) + wb (3.4 MB) < 56.7 MB
    __hip_bfloat16* xb  = (__hip_bfloat16*)d_out;
    __hip_bfloat16* wb  = xb + (size_t)NX;

    // C1/C2: fp32 -> bf16 converts into d_out scratch
    cvt_f32_bf16<<<NX / 8 / 256, 256, 0, stream>>>(x, xb, NX / 8);
    cvt_f32_bf16<<<NWQ / 8 / 256, 256, 0, stream>>>(w_qkv, wb, NWQ / 8);
    // K1: qkv = xb @ wb^T  (pure-bf16 DMA staging, bf16 C)
    gemm_a_dma<false, false><<<dim3(F3 / 128, (Mrows + 127) / 128), 256, 0, stream>>>(
        xb, EMB, wb, EMB, qkv, Mrows, F3, EMB);
    // K2: RoPE on q,k patch rows
    rope_kernel<<<dim3(576, 32), 256, 0, stream>>>(qkv);
    // K3: attention (512 thr, 128-row Q tiles); O overwrites q-region of qkv
    attn_kernel<<<dim3((S_LEN + 127) / 128, NHEAD, 32), 512, 0, stream>>>(qkv, qkv, F3);
    // K4: out = O @ bf16(w_proj)^T  (A DMA bf16 stride F3; B fp32 convert; C fp32)
    gemm_a_dma<true, true><<<dim3(EMB / 128, (Mrows + 127) / 128), 256, 0, stream>>>(
        qkv, F3, w_proj, EMB, out, Mrows, EMB, EMB);
}

// Round 3
// 379.616 us; speedup vs baseline: 1.3977x; 1.0977x over previous
//
#include <hip/hip_runtime.h>
#include <hip/hip_bf16.h>
#include <cstdint>

// ---------------------------------------------------------------------------
// RoPE Multi-Head Self-Attention, MI355X (gfx950)
// B=32, S=577, E=768, H=12, Dh=64.  Inputs fp32, output fp32 (r6-verified).
// Internally bf16 MFMA / fp32 accumulate; qkv workspace bf16.
// Round 10:
//  [C1,C2] convert x, w_qkv -> bf16 into d_out-as-scratch (dead until K4)
//  [K1] qkv = xb @ wb^T           (pure-bf16, global_load_lds DMA staging)
//  [K2] RoPE in-place on q,k patch rows
//  [K3] flash attention, 512 thr / 128-row Q tile; Ps aliased onto dead Qs.
//       NEW r10a: T14 async-STAGE split -- tile t+1's K/V global loads issue
//       right after barrier B (raw s_barrier, NO vmcnt drain) and are consumed
//       at tile t+1's barrier A; latency hides under tile t's compute.
//       NEW r10b: swapped QK^T (mfma(K,Q) -> S^T): each lane owns ONE q row's
//       64 keys -> softmax = local-reg reduce + 2 shuffles (was 4x4-deep
//       chains, 32 DS ops), scalar m/l/alpha (1 exp not 4), 4 bpermute
//       broadcasts back to O-row layout. K/Q/P/V LDS read patterns unchanged.
//  [K4] out = O @ bf16(w_proj)^T  (A via DMA, B fp32 register-convert, C fp32)
// ---------------------------------------------------------------------------

typedef __attribute__((ext_vector_type(8))) short bf16x8;  // 8 bf16 = 4 VGPRs
typedef __attribute__((ext_vector_type(4))) float f32x4;

#define MFMA16(a, b, c) __builtin_amdgcn_mfma_f32_16x16x32_bf16((a), (b), (c), 0, 0, 0)

#define S_LEN 577
#define NHEAD 12
#define DHEAD 64
#define EMB   768
#define F3    2304   // 3*EMB
#define NT_KV 10     // ceil(577/64)

// async global->LDS, 16B/lane; LDS dest must be wave-uniform base + lane*16.
__device__ __forceinline__ void gload_lds16(const __hip_bfloat16* g, __hip_bfloat16* l) {
    __builtin_amdgcn_global_load_lds(
        (const __attribute__((address_space(1))) unsigned int*)g,
        (__attribute__((address_space(3))) unsigned int*)l, 16, 0, 0);
}

// load 8 consecutive fp32, convert to bf16 packed in a uint4 (16B)
__device__ __forceinline__ uint4 load8_f32(const float* p) {
    const float4 f0 = *(const float4*)p;
    const float4 f1 = *(const float4*)(p + 4);
    union { uint4 u; __hip_bfloat16 h[8]; } r;
    r.h[0] = __float2bfloat16(f0.x); r.h[1] = __float2bfloat16(f0.y);
    r.h[2] = __float2bfloat16(f0.z); r.h[3] = __float2bfloat16(f0.w);
    r.h[4] = __float2bfloat16(f1.x); r.h[5] = __float2bfloat16(f1.y);
    r.h[6] = __float2bfloat16(f1.z); r.h[7] = __float2bfloat16(f1.w);
    return r.u;
}

// ---------------------------------------------------------------------------
// C1/C2: fp32 -> bf16 bulk convert (n must be a multiple of 8; ours are)
// ---------------------------------------------------------------------------
__global__ __launch_bounds__(256) void cvt_f32_bf16(
    const float* __restrict__ src, __hip_bfloat16* __restrict__ dst, int n8)
{
    const int i = blockIdx.x * 256 + threadIdx.x;
    if (i < n8)
        *(uint4*)(dst + (size_t)i * 8) = load8_f32(src + (size_t)i * 8);
}

// ---------------------------------------------------------------------------
// K1/K4: C[m][n] = sum_k A[m][k] * B[n][k]
// A: bf16, row stride lda, staged via global_load_lds DMA.
// B: BF32 ? fp32 register-convert staging : bf16 DMA staging. Row stride ldb.
// C: CF32 ? fp32 : bf16.  N%128==0, K%32==0; M guarded.
// 128x128 tile, BK=32, 16x16x32 MFMA, 4 waves x 4x4 acc frags (m97 structure).
// ---------------------------------------------------------------------------
template<bool BF32, bool CF32>
__global__ __launch_bounds__(256) void gemm_a_dma(
    const __hip_bfloat16* __restrict__ A, int lda,
    const void* __restrict__ Bv, int ldb,
    void* __restrict__ Cv, int M, int N, int K)
{
    __shared__ __hip_bfloat16 As[128 * 32];   // [row][k], 64B rows (DMA layout)
    __shared__ __hip_bfloat16 Bs[128 * 32];

    const int t      = threadIdx.x;
    const int l      = t & 63;
    const int w      = t >> 6;
    const int lane15 = l & 15;
    const int quad   = l >> 4;

    const int n0 = blockIdx.x * 128;
    const int m0 = blockIdx.y * 128;
    const int wm = (w >> 1) * 64;
    const int wn = (w & 1) * 64;

    const int srow   = t >> 2;   // 0..63
    const int schunk = t & 3;    // 0..3 (16B chunks)

    int ar0 = m0 + srow;       if (ar0 > M - 1) ar0 = M - 1;
    int ar1 = m0 + 64 + srow;  if (ar1 > M - 1) ar1 = M - 1;
    const int br0 = n0 + srow;
    const int br1 = n0 + 64 + srow;

    const __hip_bfloat16* pa0 = A + (size_t)ar0 * lda + schunk * 8;
    const __hip_bfloat16* pa1 = A + (size_t)ar1 * lda + schunk * 8;
    const size_t b0off = (size_t)br0 * ldb + schunk * 8;
    const size_t b1off = (size_t)br1 * ldb + schunk * 8;

    __hip_bfloat16* lAs0 = As + srow * 32 + schunk * 8;          // == As + t*8
    __hip_bfloat16* lAs1 = As + (64 + srow) * 32 + schunk * 8;
    __hip_bfloat16* lBs0 = Bs + srow * 32 + schunk * 8;
    __hip_bfloat16* lBs1 = Bs + (64 + srow) * 32 + schunk * 8;

    f32x4 acc[4][4] = {};

    for (int k0 = 0; k0 < K; k0 += 32) {
        uint4 vb0, vb1;
        if constexpr (BF32) {   // issue B global loads before barrier (overlap)
            vb0 = load8_f32((const float*)Bv + b0off + k0);
            vb1 = load8_f32((const float*)Bv + b1off + k0);
        }
        __syncthreads();        // prior iter's frag reads complete
        gload_lds16(pa0 + k0, lAs0);
        gload_lds16(pa1 + k0, lAs1);
        if constexpr (BF32) {
            *(uint4*)lBs0 = vb0;
            *(uint4*)lBs1 = vb1;
        } else {
            gload_lds16((const __hip_bfloat16*)Bv + b0off + k0, lBs0);
            gload_lds16((const __hip_bfloat16*)Bv + b1off + k0, lBs1);
        }
        __syncthreads();        // compiler drains vmcnt+lgkmcnt before barrier

        bf16x8 a[4], b[4];
        #pragma unroll
        for (int i = 0; i < 4; ++i)
            a[i] = *(const bf16x8*)(As + (wm + i * 16 + lane15) * 32 + quad * 8);
        #pragma unroll
        for (int j = 0; j < 4; ++j)
            b[j] = *(const bf16x8*)(Bs + (wn + j * 16 + lane15) * 32 + quad * 8);

        #pragma unroll
        for (int i = 0; i < 4; ++i)
            #pragma unroll
            for (int j = 0; j < 4; ++j)
                acc[i][j] = MFMA16(a[i], b[j], acc[i][j]);
    }

    // epilogue: C/D layout col=lane&15, row=quad*4+reg
    #pragma unroll
    for (int i = 0; i < 4; ++i) {
        #pragma unroll
        for (int r = 0; r < 4; ++r) {
            const int m = m0 + wm + i * 16 + quad * 4 + r;
            if (m < M) {
                #pragma unroll
                for (int j = 0; j < 4; ++j) {
                    const int n = n0 + wn + j * 16 + lane15;
                    if constexpr (CF32)
                        ((float*)Cv)[(size_t)m * N + n] = acc[i][j][r];
                    else
                        ((__hip_bfloat16*)Cv)[(size_t)m * N + n] = __float2bfloat16(acc[i][j][r]);
                }
            }
        }
    }
}

// ---------------------------------------------------------------------------
// K2: RoPE in-place on q and k for patch tokens (s >= 1) — r6-verified.
// ---------------------------------------------------------------------------
__global__ __launch_bounds__(256) void rope_kernel(__hip_bfloat16* __restrict__ qkv)
{
    const int p = blockIdx.x;    // 0..575 patch index
    const int b = blockIdx.y;
    const int l = threadIdx.x & 63;
    const int w = threadIdx.x >> 6;

    const int jj   = l & 31;
    const float i2 = (float)((jj >> 1) * 2);
    const float dv = __expf(-i2 * 0.28782313662425576f);   // ln(10000)/32
    const float inv = 1.0f / (23.0f + 1e-8f);
    const float cx = (float)(p % 24) * inv;
    const float cy = (float)(p / 24) * inv;
    const float ang = ((l < 32) ? cx : cy) * dv;
    const float c = __cosf(ang);
    const float s = __sinf(ang);
    const int nb = (l & 32) | ((jj + 31) & 31);   // lane of (j-1)%32, same half

    const size_t rowbase = ((size_t)(b * S_LEN + 1 + p)) * F3;

    for (int pr = w; pr < 24; pr += 4) {
        const int part = pr / 12;    // 0=q, 1=k
        const int h    = pr % 12;
        const size_t off = rowbase + (size_t)part * EMB + h * DHEAD + l;
        float v  = __bfloat162float(qkv[off]);
        float vp = __shfl(v, nb, 64);
        qkv[off] = __float2bfloat16(v * c + vp * s);
    }
}

// ---------------------------------------------------------------------------
// K3: MFMA flash attention, 512 threads (8 waves), Q tile = 128 rows.
// grid (qt=5, h=12, b=32). Wave w owns q rows w*16..w*16+15 of the tile.
// Q pre-scaled by 0.125. O written with row stride ldo (aliased onto qkv's
// q-region; each block overwrites exactly the q-cells only it reads).
//
// Ps aliased onto the Qs LDS region (Qs dead after frag load): LDS 36864 B
// -> 4 blocks/CU.  P write rows are wave-private (w*16+lane15), so the P
// round-trip needs only a same-wave lgkmcnt drain.
//
// r10a T14 async-STAGE: tile t+1's K/V global loads issue before barrier B;
// barrier B is raw s_barrier + lgkmcnt(0) only (NO vmcnt drain) so the loads
// stay in flight across the compute phase.  Barrier A (__syncthreads) drains
// vmcnt right where the data is consumed (LDS staging writes).
//
// r10b swapped QK^T: sf = mfma(Kfrag, Qfrag) gives S^T[key][q]; lane owns
// q=lane15's 64 keys (16 regs + quad-folds at xor16/xor32).  Scalar m/l.
// alpha/l broadcast to O-layout rows (q=quad*4+r) via 4 lane-reads.
// ---------------------------------------------------------------------------
__global__ __launch_bounds__(512) void attn_kernel(
    const __hip_bfloat16* __restrict__ qkv,
    __hip_bfloat16* __restrict__ attn_out, int ldo)
{
    __shared__ __hip_bfloat16 Qs[128][72];     // Q frags, then aliased as Ps
    __shared__ __hip_bfloat16 Ks[64][72];
    __shared__ __hip_bfloat16 Vt[64][72];      // transposed: Vt[d][s]

    const int t      = threadIdx.x;
    const int l      = t & 63;
    const int w      = t >> 6;     // 0..7
    const int lane15 = l & 15;
    const int quad   = l >> 4;

    const int q0 = blockIdx.x * 128;
    const int h  = blockIdx.y;
    const int b  = blockIdx.z;

    // staging index split (fixed per thread)
    const int krow = t >> 3, kseg = t & 7;   // K: row 0..63, 16B chunk 0..7
    const int vs   = t & 63, vdg = t >> 6;   // V: s 0..63, dim-group 0..7

    // ---- issue tile-0 K/V prefetch ----
    uint4 ku, vu;
    {
        int gk = krow; if (gk > S_LEN - 1) gk = S_LEN - 1;
        ku = ((const uint4*)(qkv + (size_t)(b * S_LEN + gk) * F3 + EMB + h * DHEAD))[kseg];
        int gv = vs;  if (gv > S_LEN - 1) gv = S_LEN - 1;
        vu = ((const uint4*)(qkv + (size_t)(b * S_LEN + gv) * F3 + 2 * EMB + h * DHEAD))[vdg];
    }

    // ---- stage Q (scaled): row = t>>2 (0..127), seg = t&3 (16 elems) ----
    {
        const int row = t >> 2, seg = t & 3;
        int gq = q0 + row; if (gq > S_LEN - 1) gq = S_LEN - 1;
        const uint4* src = (const uint4*)(qkv + (size_t)(b * S_LEN + gq) * F3 + h * DHEAD + seg * 16);
        uint4 u0 = src[0], u1 = src[1];
        const __hip_bfloat16* e0 = (const __hip_bfloat16*)&u0;
        const __hip_bfloat16* e1 = (const __hip_bfloat16*)&u1;
        #pragma unroll
        for (int i = 0; i < 8; ++i) {
            Qs[row][seg * 16 + i]     = __float2bfloat16(__bfloat162float(e0[i]) * 0.125f);
            Qs[row][seg * 16 + 8 + i] = __float2bfloat16(__bfloat162float(e1[i]) * 0.125f);
        }
    }
    __syncthreads();

    // B-operand frags for Q: B[n=lane&15 (q row)][k=quad*8+j]  (held whole loop)
    bf16x8 qf0 = *(const bf16x8*)&Qs[w * 16 + lane15][quad * 8];
    bf16x8 qf1 = *(const bf16x8*)&Qs[w * 16 + lane15][32 + quad * 8];

    f32x4 o[4] = {};                       // O[q=quad*4+r][d=ci*16+lane15]
    float m_i = -3.0e38f;                  // softmax state for q = lane15 (scalar)
    float l_i = 0.f;

    for (int ti = 0; ti < NT_KV; ++ti) {
        __syncthreads();   // A: prior tile's LDS reads done; vmcnt drain = consume prefetch
        // ---- write prefetched K tile: Ks[krow][kseg*8..] ----
        *(uint4*)&Ks[krow][kseg * 8] = ku;
        // ---- write prefetched V tile transposed ----
        {
            const __hip_bfloat16* e0 = (const __hip_bfloat16*)&vu;
            #pragma unroll
            for (int i = 0; i < 8; ++i)
                Vt[vdg * 8 + i][vs] = e0[i];
        }
        // ---- issue NEXT tile's K/V prefetch (stays in flight across B) ----
        if (ti + 1 < NT_KV) {
            int gk = (ti + 1) * 64 + krow; if (gk > S_LEN - 1) gk = S_LEN - 1;
            ku = ((const uint4*)(qkv + (size_t)(b * S_LEN + gk) * F3 + EMB + h * DHEAD))[kseg];
            int gv = (ti + 1) * 64 + vs;  if (gv > S_LEN - 1) gv = S_LEN - 1;
            vu = ((const uint4*)(qkv + (size_t)(b * S_LEN + gv) * F3 + 2 * EMB + h * DHEAD))[vdg];
        }
        // B: LDS writes visible; do NOT drain vmcnt (prefetch in flight)
        asm volatile("s_waitcnt lgkmcnt(0)" ::: "memory");
        __builtin_amdgcn_s_barrier();
        asm volatile("" ::: "memory");

        // ---- S^T = K Q^T: sf[nt][r] = S[key=nt*16+quad*4+r][q=lane15] ----
        f32x4 sf[4];
        #pragma unroll
        for (int nt = 0; nt < 4; ++nt) {
            f32x4 z = {0.f, 0.f, 0.f, 0.f};
            bf16x8 k0f = *(const bf16x8*)&Ks[nt * 16 + lane15][quad * 8];
            bf16x8 k1f = *(const bf16x8*)&Ks[nt * 16 + lane15][32 + quad * 8];
            z = MFMA16(k0f, qf0, z);
            z = MFMA16(k1f, qf1, z);
            sf[nt] = z;
        }
        const int s0 = ti * 64;
        #pragma unroll
        for (int nt = 0; nt < 4; ++nt)
            #pragma unroll
            for (int r = 0; r < 4; ++r)
                if (s0 + nt * 16 + quad * 4 + r >= S_LEN) sf[nt][r] = -1e30f;

        // ---- row max for q=lane15: 16 local + fold across quads ----
        float mx = fmaxf(fmaxf(sf[0][0], sf[0][1]), fmaxf(sf[0][2], sf[0][3]));
        #pragma unroll
        for (int nt = 1; nt < 4; ++nt)
            mx = fmaxf(mx, fmaxf(fmaxf(sf[nt][0], sf[nt][1]), fmaxf(sf[nt][2], sf[nt][3])));
        mx = fmaxf(mx, __shfl_xor(mx, 16, 64));
        mx = fmaxf(mx, __shfl_xor(mx, 32, 64));

        const float mnew  = fmaxf(m_i, mx);
        const float alpha = __expf(m_i - mnew);
        m_i = mnew;

        // ---- P = exp(S - m), row sum ----
        float sum = 0.f;
        #pragma unroll
        for (int nt = 0; nt < 4; ++nt) {
            #pragma unroll
            for (int r = 0; r < 4; ++r) {
                sf[nt][r] = __expf(sf[nt][r] - mnew);
                sum += sf[nt][r];
            }
        }
        sum += __shfl_xor(sum, 16, 64);
        sum += __shfl_xor(sum, 32, 64);
        l_i = l_i * alpha + sum;

        // ---- broadcast alpha to O-layout rows (q = quad*4+r lives in lane quad*4+r) ----
        float af[4];
        #pragma unroll
        for (int r = 0; r < 4; ++r)
            af[r] = __shfl(alpha, quad * 4 + r, 64);
        #pragma unroll
        for (int ci = 0; ci < 4; ++ci)
            #pragma unroll
            for (int r = 0; r < 4; ++r)
                o[ci][r] *= af[r];

        // ---- P: S^T lane layout -> LDS [q][key] (wave-private rows) ----
        #pragma unroll
        for (int nt = 0; nt < 4; ++nt)
            #pragma unroll
            for (int r = 0; r < 4; ++r)
                Qs[w * 16 + lane15][nt * 16 + quad * 4 + r] = __float2bfloat16(sf[nt][r]);
        asm volatile("s_waitcnt lgkmcnt(0)" ::: "memory");

        // ---- O += P V ----
        #pragma unroll
        for (int s32 = 0; s32 < 2; ++s32) {
            bf16x8 pa = *(const bf16x8*)&Qs[w * 16 + lane15][s32 * 32 + quad * 8];
            #pragma unroll
            for (int ci = 0; ci < 4; ++ci) {
                bf16x8 vb = *(const bf16x8*)&Vt[ci * 16 + lane15][s32 * 32 + quad * 8];
                o[ci] = MFMA16(pa, vb, o[ci]);
            }
        }
    }

    // ---- epilogue: O / l -> attn_out; l for row q=quad*4+r from lane quad*4+r ----
    #pragma unroll
    for (int r = 0; r < 4; ++r) {
        const float lr = __shfl(l_i, quad * 4 + r, 64);
        const int q = q0 + w * 16 + quad * 4 + r;
        if (q < S_LEN) {
            const float rl = 1.0f / lr;
            #pragma unroll
            for (int ci = 0; ci < 4; ++ci) {
                attn_out[(size_t)(b * S_LEN + q) * ldo + h * DHEAD + ci * 16 + lane15] =
                    __float2bfloat16(o[ci][r] * rl);
            }
        }
    }
}

// ---------------------------------------------------------------------------
extern "C" void kernel_launch(void* const* d_in, const int* in_sizes, int n_in,
                              void* d_out, int out_size, void* d_ws, size_t ws_size,
                              hipStream_t stream) {
    const float* x      = (const float*)d_in[0];
    const float* w_qkv  = (const float*)d_in[1];
    const float* w_proj = (const float*)d_in[2];
    for (int i = 0; i < n_in; ++i) {
        if      (in_sizes[i] == 32 * S_LEN * EMB) x      = (const float*)d_in[i];
        else if (in_sizes[i] == F3 * EMB)         w_qkv  = (const float*)d_in[i];
        else if (in_sizes[i] == EMB * EMB)        w_proj = (const float*)d_in[i];
    }
    float* out = (float*)d_out;     // fp32 output (r6-verified)

    const int Mrows = 32 * S_LEN;           // 18464
    const int NX    = Mrows * EMB;          // 14,180,352 (mult of 8)
    const int NWQ   = F3 * EMB;             // 1,769,472  (mult of 8)

    __hip_bfloat16* qkv = (__hip_bfloat16*)d_ws;        // [M][2304] bf16, 81.1 MiB
    // d_out as scratch until K4 overwrites it: xb (28.4 MB) + wb (3.4 MB) < 56.7 MB
    __hip_bfloat16* xb  = (__hip_bfloat16*)d_out;
    __hip_bfloat16* wb  = xb + (size_t)NX;

    // C1/C2: fp32 -> bf16 converts into d_out scratch
    cvt_f32_bf16<<<NX / 8 / 256, 256, 0, stream>>>(x, xb, NX / 8);
    cvt_f32_bf16<<<NWQ / 8 / 256, 256, 0, stream>>>(w_qkv, wb, NWQ / 8);
    // K1: qkv = xb @ wb^T  (pure-bf16 DMA staging, bf16 C)
    gemm_a_dma<false, false><<<dim3(F3 / 128, (Mrows + 127) / 128), 256, 0, stream>>>(
        xb, EMB, wb, EMB, qkv, Mrows, F3, EMB);
    // K2: RoPE on q,k patch rows
    rope_kernel<<<dim3(576, 32), 256, 0, stream>>>(qkv);
    // K3: attention (512 thr, 128-row Q tiles); O overwrites q-region of qkv
    attn_kernel<<<dim3((S_LEN + 127) / 128, NHEAD, 32), 512, 0, stream>>>(qkv, qkv, F3);
    // K4: out = O @ bf16(w_proj)^T  (A DMA bf16 stride F3; B fp32 convert; C fp32)
    gemm_a_dma<true, true><<<dim3(EMB / 128, (Mrows + 127) / 128), 256, 0, stream>>>(
        qkv, F3, w_proj, EMB, out, Mrows, EMB, EMB);
}

// Round 4
// 378.815 us; speedup vs baseline: 1.4006x; 1.0021x over previous
//
#include <hip/hip_runtime.h>
#include <hip/hip_bf16.h>
#include <cstdint>

// ---------------------------------------------------------------------------
// RoPE Multi-Head Self-Attention, MI355X (gfx950)
// B=32, S=577, E=768, H=12, Dh=64.  Inputs fp32, output fp32 (r6-verified).
// Internally bf16 MFMA / fp32 accumulate; qkv workspace bf16.
// Round 11:
//  [C1,C2] convert x, w_qkv -> bf16 into d_out-as-scratch (dead until K4)
//  [K1] qkv = xb @ wb^T           (pure-bf16, global_load_lds DMA staging)
//       NEW r11: chunk-XOR LDS swizzle.  As/Bs rows are 64B; the old layout
//       put the 4 even lanes of each 8-lane phase group on the SAME 4-bank
//       group (4-way conflict; SQ_LDS_BANK_CONFLICT=8.0e6/dispatch ~ 11% of
//       cycles).  Slot s of row r now holds global chunk s^((r>>1)&3).
//       gload_lds dest must stay linear (rule: swizzle both sides via the
//       GLOBAL source) -> staging source chunk = schunk^((t>>3)&3); frag
//       reads use quad^((lane15>>1)&3).  Both are per-thread constants.
//  [K2] RoPE in-place on q,k patch rows
//  [K3] flash attention (r10: async K/V prefetch + swapped QK^T softmax)
//  [K4] out = O @ bf16(w_proj)^T  (same swizzle; B fp32 register-convert)
// ---------------------------------------------------------------------------

typedef __attribute__((ext_vector_type(8))) short bf16x8;  // 8 bf16 = 4 VGPRs
typedef __attribute__((ext_vector_type(4))) float f32x4;

#define MFMA16(a, b, c) __builtin_amdgcn_mfma_f32_16x16x32_bf16((a), (b), (c), 0, 0, 0)

#define S_LEN 577
#define NHEAD 12
#define DHEAD 64
#define EMB   768
#define F3    2304   // 3*EMB
#define NT_KV 10     // ceil(577/64)

// async global->LDS, 16B/lane; LDS dest must be wave-uniform base + lane*16.
__device__ __forceinline__ void gload_lds16(const __hip_bfloat16* g, __hip_bfloat16* l) {
    __builtin_amdgcn_global_load_lds(
        (const __attribute__((address_space(1))) unsigned int*)g,
        (__attribute__((address_space(3))) unsigned int*)l, 16, 0, 0);
}

// load 8 consecutive fp32, convert to bf16 packed in a uint4 (16B)
__device__ __forceinline__ uint4 load8_f32(const float* p) {
    const float4 f0 = *(const float4*)p;
    const float4 f1 = *(const float4*)(p + 4);
    union { uint4 u; __hip_bfloat16 h[8]; } r;
    r.h[0] = __float2bfloat16(f0.x); r.h[1] = __float2bfloat16(f0.y);
    r.h[2] = __float2bfloat16(f0.z); r.h[3] = __float2bfloat16(f0.w);
    r.h[4] = __float2bfloat16(f1.x); r.h[5] = __float2bfloat16(f1.y);
    r.h[6] = __float2bfloat16(f1.z); r.h[7] = __float2bfloat16(f1.w);
    return r.u;
}

// ---------------------------------------------------------------------------
// C1/C2: fp32 -> bf16 bulk convert (n must be a multiple of 8; ours are)
// ---------------------------------------------------------------------------
__global__ __launch_bounds__(256) void cvt_f32_bf16(
    const float* __restrict__ src, __hip_bfloat16* __restrict__ dst, int n8)
{
    const int i = blockIdx.x * 256 + threadIdx.x;
    if (i < n8)
        *(uint4*)(dst + (size_t)i * 8) = load8_f32(src + (size_t)i * 8);
}

// ---------------------------------------------------------------------------
// K1/K4: C[m][n] = sum_k A[m][k] * B[n][k]
// A: bf16, row stride lda, staged via global_load_lds DMA.
// B: BF32 ? fp32 register-convert staging : bf16 DMA staging. Row stride ldb.
// C: CF32 ? fp32 : bf16.  N%128==0, K%32==0; M guarded.
// 128x128 tile, BK=32, 16x16x32 MFMA, 4 waves x 4x4 acc frags (m97 structure).
// r11: chunk-XOR swizzle -- LDS slot s of row r holds global chunk
// s ^ ((r>>1)&3).  Staging pre-swizzles the GLOBAL source (gload_lds dest is
// forced-linear); frag reads invert with quad ^ ((lane15>>1)&3).
// ---------------------------------------------------------------------------
template<bool BF32, bool CF32>
__global__ __launch_bounds__(256) void gemm_a_dma(
    const __hip_bfloat16* __restrict__ A, int lda,
    const void* __restrict__ Bv, int ldb,
    void* __restrict__ Cv, int M, int N, int K)
{
    __shared__ __hip_bfloat16 As[128 * 32];   // [row][k-swizzled], 64B rows
    __shared__ __hip_bfloat16 Bs[128 * 32];

    const int t      = threadIdx.x;
    const int l      = t & 63;
    const int w      = t >> 6;
    const int lane15 = l & 15;
    const int quad   = l >> 4;

    const int n0 = blockIdx.x * 128;
    const int m0 = blockIdx.y * 128;
    const int wm = (w >> 1) * 64;
    const int wn = (w & 1) * 64;

    const int srow   = t >> 2;   // 0..63
    const int schunk = t & 3;    // 0..3 (16B chunks)
    // swizzle: LDS slot schunk of row srow (and srow+64) gets global chunk
    // schunk ^ fsw;  fsw = ((srow)>>1)&3 = (t>>3)&3  (row+64 unchanged mod 4)
    const int fsw    = (t >> 3) & 3;
    const int gchunk = schunk ^ fsw;

    int ar0 = m0 + srow;       if (ar0 > M - 1) ar0 = M - 1;
    int ar1 = m0 + 64 + srow;  if (ar1 > M - 1) ar1 = M - 1;
    const int br0 = n0 + srow;
    const int br1 = n0 + 64 + srow;

    const __hip_bfloat16* pa0 = A + (size_t)ar0 * lda + gchunk * 8;
    const __hip_bfloat16* pa1 = A + (size_t)ar1 * lda + gchunk * 8;
    const size_t b0off = (size_t)br0 * ldb + gchunk * 8;
    const size_t b1off = (size_t)br1 * ldb + gchunk * 8;

    __hip_bfloat16* lAs0 = As + srow * 32 + schunk * 8;          // == As + t*8
    __hip_bfloat16* lAs1 = As + (64 + srow) * 32 + schunk * 8;
    __hip_bfloat16* lBs0 = Bs + srow * 32 + schunk * 8;
    __hip_bfloat16* lBs1 = Bs + (64 + srow) * 32 + schunk * 8;

    // read-side swizzle: row = wm|wn + i*16 + lane15 -> ((row>>1)&3) ==
    // ((lane15>>1)&3) since wm/wn/i*16 are multiples of 16.
    const int rsw = (quad ^ ((lane15 >> 1) & 3)) * 8;

    f32x4 acc[4][4] = {};

    for (int k0 = 0; k0 < K; k0 += 32) {
        uint4 vb0, vb1;
        if constexpr (BF32) {   // issue B global loads before barrier (overlap)
            vb0 = load8_f32((const float*)Bv + b0off + k0);
            vb1 = load8_f32((const float*)Bv + b1off + k0);
        }
        __syncthreads();        // prior iter's frag reads complete
        gload_lds16(pa0 + k0, lAs0);
        gload_lds16(pa1 + k0, lAs1);
        if constexpr (BF32) {
            *(uint4*)lBs0 = vb0;
            *(uint4*)lBs1 = vb1;
        } else {
            gload_lds16((const __hip_bfloat16*)Bv + b0off + k0, lBs0);
            gload_lds16((const __hip_bfloat16*)Bv + b1off + k0, lBs1);
        }
        __syncthreads();        // compiler drains vmcnt+lgkmcnt before barrier

        bf16x8 a[4], b[4];
        #pragma unroll
        for (int i = 0; i < 4; ++i)
            a[i] = *(const bf16x8*)(As + (wm + i * 16 + lane15) * 32 + rsw);
        #pragma unroll
        for (int j = 0; j < 4; ++j)
            b[j] = *(const bf16x8*)(Bs + (wn + j * 16 + lane15) * 32 + rsw);

        #pragma unroll
        for (int i = 0; i < 4; ++i)
            #pragma unroll
            for (int j = 0; j < 4; ++j)
                acc[i][j] = MFMA16(a[i], b[j], acc[i][j]);
    }

    // epilogue: C/D layout col=lane&15, row=quad*4+reg
    #pragma unroll
    for (int i = 0; i < 4; ++i) {
        #pragma unroll
        for (int r = 0; r < 4; ++r) {
            const int m = m0 + wm + i * 16 + quad * 4 + r;
            if (m < M) {
                #pragma unroll
                for (int j = 0; j < 4; ++j) {
                    const int n = n0 + wn + j * 16 + lane15;
                    if constexpr (CF32)
                        ((float*)Cv)[(size_t)m * N + n] = acc[i][j][r];
                    else
                        ((__hip_bfloat16*)Cv)[(size_t)m * N + n] = __float2bfloat16(acc[i][j][r]);
                }
            }
        }
    }
}

// ---------------------------------------------------------------------------
// K2: RoPE in-place on q and k for patch tokens (s >= 1) — r6-verified.
// ---------------------------------------------------------------------------
__global__ __launch_bounds__(256) void rope_kernel(__hip_bfloat16* __restrict__ qkv)
{
    const int p = blockIdx.x;    // 0..575 patch index
    const int b = blockIdx.y;
    const int l = threadIdx.x & 63;
    const int w = threadIdx.x >> 6;

    const int jj   = l & 31;
    const float i2 = (float)((jj >> 1) * 2);
    const float dv = __expf(-i2 * 0.28782313662425576f);   // ln(10000)/32
    const float inv = 1.0f / (23.0f + 1e-8f);
    const float cx = (float)(p % 24) * inv;
    const float cy = (float)(p / 24) * inv;
    const float ang = ((l < 32) ? cx : cy) * dv;
    const float c = __cosf(ang);
    const float s = __sinf(ang);
    const int nb = (l & 32) | ((jj + 31) & 31);   // lane of (j-1)%32, same half

    const size_t rowbase = ((size_t)(b * S_LEN + 1 + p)) * F3;

    for (int pr = w; pr < 24; pr += 4) {
        const int part = pr / 12;    // 0=q, 1=k
        const int h    = pr % 12;
        const size_t off = rowbase + (size_t)part * EMB + h * DHEAD + l;
        float v  = __bfloat162float(qkv[off]);
        float vp = __shfl(v, nb, 64);
        qkv[off] = __float2bfloat16(v * c + vp * s);
    }
}

// ---------------------------------------------------------------------------
// K3: MFMA flash attention, 512 threads (8 waves), Q tile = 128 rows.
// grid (qt=5, h=12, b=32). Wave w owns q rows w*16..w*16+15 of the tile.
// Q pre-scaled by 0.125. O written with row stride ldo (aliased onto qkv's
// q-region; each block overwrites exactly the q-cells only it reads).
//
// Ps aliased onto the Qs LDS region (Qs dead after frag load): LDS 36864 B
// -> 4 blocks/CU.  P write rows are wave-private (w*16+lane15), so the P
// round-trip needs only a same-wave lgkmcnt drain.
//
// r10a T14 async-STAGE: tile t+1's K/V global loads issue before barrier B;
// barrier B is raw s_barrier + lgkmcnt(0) only (NO vmcnt drain) so the loads
// stay in flight across the compute phase.  Barrier A (__syncthreads) drains
// vmcnt right where the data is consumed (LDS staging writes).
//
// r10b swapped QK^T: sf = mfma(Kfrag, Qfrag) gives S^T[key][q]; lane owns
// q=lane15's 64 keys (16 regs + quad-folds at xor16/xor32).  Scalar m/l.
// alpha/l broadcast to O-layout rows (q=quad*4+r) via 4 lane-reads.
// ---------------------------------------------------------------------------
__global__ __launch_bounds__(512) void attn_kernel(
    const __hip_bfloat16* __restrict__ qkv,
    __hip_bfloat16* __restrict__ attn_out, int ldo)
{
    __shared__ __hip_bfloat16 Qs[128][72];     // Q frags, then aliased as Ps
    __shared__ __hip_bfloat16 Ks[64][72];
    __shared__ __hip_bfloat16 Vt[64][72];      // transposed: Vt[d][s]

    const int t      = threadIdx.x;
    const int l      = t & 63;
    const int w      = t >> 6;     // 0..7
    const int lane15 = l & 15;
    const int quad   = l >> 4;

    const int q0 = blockIdx.x * 128;
    const int h  = blockIdx.y;
    const int b  = blockIdx.z;

    // staging index split (fixed per thread)
    const int krow = t >> 3, kseg = t & 7;   // K: row 0..63, 16B chunk 0..7
    const int vs   = t & 63, vdg = t >> 6;   // V: s 0..63, dim-group 0..7

    // ---- issue tile-0 K/V prefetch ----
    uint4 ku, vu;
    {
        int gk = krow; if (gk > S_LEN - 1) gk = S_LEN - 1;
        ku = ((const uint4*)(qkv + (size_t)(b * S_LEN + gk) * F3 + EMB + h * DHEAD))[kseg];
        int gv = vs;  if (gv > S_LEN - 1) gv = S_LEN - 1;
        vu = ((const uint4*)(qkv + (size_t)(b * S_LEN + gv) * F3 + 2 * EMB + h * DHEAD))[vdg];
    }

    // ---- stage Q (scaled): row = t>>2 (0..127), seg = t&3 (16 elems) ----
    {
        const int row = t >> 2, seg = t & 3;
        int gq = q0 + row; if (gq > S_LEN - 1) gq = S_LEN - 1;
        const uint4* src = (const uint4*)(qkv + (size_t)(b * S_LEN + gq) * F3 + h * DHEAD + seg * 16);
        uint4 u0 = src[0], u1 = src[1];
        const __hip_bfloat16* e0 = (const __hip_bfloat16*)&u0;
        const __hip_bfloat16* e1 = (const __hip_bfloat16*)&u1;
        #pragma unroll
        for (int i = 0; i < 8; ++i) {
            Qs[row][seg * 16 + i]     = __float2bfloat16(__bfloat162float(e0[i]) * 0.125f);
            Qs[row][seg * 16 + 8 + i] = __float2bfloat16(__bfloat162float(e1[i]) * 0.125f);
        }
    }
    __syncthreads();

    // B-operand frags for Q: B[n=lane&15 (q row)][k=quad*8+j]  (held whole loop)
    bf16x8 qf0 = *(const bf16x8*)&Qs[w * 16 + lane15][quad * 8];
    bf16x8 qf1 = *(const bf16x8*)&Qs[w * 16 + lane15][32 + quad * 8];

    f32x4 o[4] = {};                       // O[q=quad*4+r][d=ci*16+lane15]
    float m_i = -3.0e38f;                  // softmax state for q = lane15 (scalar)
    float l_i = 0.f;

    for (int ti = 0; ti < NT_KV; ++ti) {
        __syncthreads();   // A: prior tile's LDS reads done; vmcnt drain = consume prefetch
        // ---- write prefetched K tile: Ks[krow][kseg*8..] ----
        *(uint4*)&Ks[krow][kseg * 8] = ku;
        // ---- write prefetched V tile transposed ----
        {
            const __hip_bfloat16* e0 = (const __hip_bfloat16*)&vu;
            #pragma unroll
            for (int i = 0; i < 8; ++i)
                Vt[vdg * 8 + i][vs] = e0[i];
        }
        // ---- issue NEXT tile's K/V prefetch (stays in flight across B) ----
        if (ti + 1 < NT_KV) {
            int gk = (ti + 1) * 64 + krow; if (gk > S_LEN - 1) gk = S_LEN - 1;
            ku = ((const uint4*)(qkv + (size_t)(b * S_LEN + gk) * F3 + EMB + h * DHEAD))[kseg];
            int gv = (ti + 1) * 64 + vs;  if (gv > S_LEN - 1) gv = S_LEN - 1;
            vu = ((const uint4*)(qkv + (size_t)(b * S_LEN + gv) * F3 + 2 * EMB + h * DHEAD))[vdg];
        }
        // B: LDS writes visible; do NOT drain vmcnt (prefetch in flight)
        asm volatile("s_waitcnt lgkmcnt(0)" ::: "memory");
        __builtin_amdgcn_s_barrier();
        asm volatile("" ::: "memory");

        // ---- S^T = K Q^T: sf[nt][r] = S[key=nt*16+quad*4+r][q=lane15] ----
        f32x4 sf[4];
        #pragma unroll
        for (int nt = 0; nt < 4; ++nt) {
            f32x4 z = {0.f, 0.f, 0.f, 0.f};
            bf16x8 k0f = *(const bf16x8*)&Ks[nt * 16 + lane15][quad * 8];
            bf16x8 k1f = *(const bf16x8*)&Ks[nt * 16 + lane15][32 + quad * 8];
            z = MFMA16(k0f, qf0, z);
            z = MFMA16(k1f, qf1, z);
            sf[nt] = z;
        }
        const int s0 = ti * 64;
        #pragma unroll
        for (int nt = 0; nt < 4; ++nt)
            #pragma unroll
            for (int r = 0; r < 4; ++r)
                if (s0 + nt * 16 + quad * 4 + r >= S_LEN) sf[nt][r] = -1e30f;

        // ---- row max for q=lane15: 16 local + fold across quads ----
        float mx = fmaxf(fmaxf(sf[0][0], sf[0][1]), fmaxf(sf[0][2], sf[0][3]));
        #pragma unroll
        for (int nt = 1; nt < 4; ++nt)
            mx = fmaxf(mx, fmaxf(fmaxf(sf[nt][0], sf[nt][1]), fmaxf(sf[nt][2], sf[nt][3])));
        mx = fmaxf(mx, __shfl_xor(mx, 16, 64));
        mx = fmaxf(mx, __shfl_xor(mx, 32, 64));

        const float mnew  = fmaxf(m_i, mx);
        const float alpha = __expf(m_i - mnew);
        m_i = mnew;

        // ---- P = exp(S - m), row sum ----
        float sum = 0.f;
        #pragma unroll
        for (int nt = 0; nt < 4; ++nt) {
            #pragma unroll
            for (int r = 0; r < 4; ++r) {
                sf[nt][r] = __expf(sf[nt][r] - mnew);
                sum += sf[nt][r];
            }
        }
        sum += __shfl_xor(sum, 16, 64);
        sum += __shfl_xor(sum, 32, 64);
        l_i = l_i * alpha + sum;

        // ---- broadcast alpha to O-layout rows (q = quad*4+r lives in lane quad*4+r) ----
        float af[4];
        #pragma unroll
        for (int r = 0; r < 4; ++r)
            af[r] = __shfl(alpha, quad * 4 + r, 64);
        #pragma unroll
        for (int ci = 0; ci < 4; ++ci)
            #pragma unroll
            for (int r = 0; r < 4; ++r)
                o[ci][r] *= af[r];

        // ---- P: S^T lane layout -> LDS [q][key] (wave-private rows) ----
        #pragma unroll
        for (int nt = 0; nt < 4; ++nt)
            #pragma unroll
            for (int r = 0; r < 4; ++r)
                Qs[w * 16 + lane15][nt * 16 + quad * 4 + r] = __float2bfloat16(sf[nt][r]);
        asm volatile("s_waitcnt lgkmcnt(0)" ::: "memory");

        // ---- O += P V ----
        #pragma unroll
        for (int s32 = 0; s32 < 2; ++s32) {
            bf16x8 pa = *(const bf16x8*)&Qs[w * 16 + lane15][s32 * 32 + quad * 8];
            #pragma unroll
            for (int ci = 0; ci < 4; ++ci) {
                bf16x8 vb = *(const bf16x8*)&Vt[ci * 16 + lane15][s32 * 32 + quad * 8];
                o[ci] = MFMA16(pa, vb, o[ci]);
            }
        }
    }

    // ---- epilogue: O / l -> attn_out; l for row q=quad*4+r from lane quad*4+r ----
    #pragma unroll
    for (int r = 0; r < 4; ++r) {
        const float lr = __shfl(l_i, quad * 4 + r, 64);
        const int q = q0 + w * 16 + quad * 4 + r;
        if (q < S_LEN) {
            const float rl = 1.0f / lr;
            #pragma unroll
            for (int ci = 0; ci < 4; ++ci) {
                attn_out[(size_t)(b * S_LEN + q) * ldo + h * DHEAD + ci * 16 + lane15] =
                    __float2bfloat16(o[ci][r] * rl);
            }
        }
    }
}

// ---------------------------------------------------------------------------
extern "C" void kernel_launch(void* const* d_in, const int* in_sizes, int n_in,
                              void* d_out, int out_size, void* d_ws, size_t ws_size,
                              hipStream_t stream) {
    const float* x      = (const float*)d_in[0];
    const float* w_qkv  = (const float*)d_in[1];
    const float* w_proj = (const float*)d_in[2];
    for (int i = 0; i < n_in; ++i) {
        if      (in_sizes[i] == 32 * S_LEN * EMB) x      = (const float*)d_in[i];
        else if (in_sizes[i] == F3 * EMB)         w_qkv  = (const float*)d_in[i];
        else if (in_sizes[i] == EMB * EMB)        w_proj = (const float*)d_in[i];
    }
    float* out = (float*)d_out;     // fp32 output (r6-verified)

    const int Mrows = 32 * S_LEN;           // 18464
    const int NX    = Mrows * EMB;          // 14,180,352 (mult of 8)
    const int NWQ   = F3 * EMB;             // 1,769,472  (mult of 8)

    __hip_bfloat16* qkv = (__hip_bfloat16*)d_ws;        // [M][2304] bf16, 81.1 MiB
    // d_out as scratch until K4 overwrites it: xb (28.4 MB) + wb (3.4 MB) < 56.7 MB
    __hip_bfloat16* xb  = (__hip_bfloat16*)d_out;
    __hip_bfloat16* wb  = xb + (size_t)NX;

    // C1/C2: fp32 -> bf16 converts into d_out scratch
    cvt_f32_bf16<<<NX / 8 / 256, 256, 0, stream>>>(x, xb, NX / 8);
    cvt_f32_bf16<<<NWQ / 8 / 256, 256, 0, stream>>>(w_qkv, wb, NWQ / 8);
    // K1: qkv = xb @ wb^T  (pure-bf16 DMA staging, bf16 C)
    gemm_a_dma<false, false><<<dim3(F3 / 128, (Mrows + 127) / 128), 256, 0, stream>>>(
        xb, EMB, wb, EMB, qkv, Mrows, F3, EMB);
    // K2: RoPE on q,k patch rows
    rope_kernel<<<dim3(576, 32), 256, 0, stream>>>(qkv);
    // K3: attention (512 thr, 128-row Q tiles); O overwrites q-region of qkv
    attn_kernel<<<dim3((S_LEN + 127) / 128, NHEAD, 32), 512, 0, stream>>>(qkv, qkv, F3);
    // K4: out = O @ bf16(w_proj)^T  (A DMA bf16 stride F3; B fp32 convert; C fp32)
    gemm_a_dma<true, true><<<dim3(EMB / 128, (Mrows + 127) / 128), 256, 0, stream>>>(
        qkv, F3, w_proj, EMB, out, Mrows, EMB, EMB);
}